// Round 8
// baseline (212.761 us; speedup 1.0000x reference)
//
#include <hip/hip_runtime.h>
#include <hip/hip_bf16.h>

typedef __bf16 bf16_t;
typedef bf16_t bf16x8 __attribute__((ext_vector_type(8)));
typedef float f32x4 __attribute__((ext_vector_type(4)));

#define NB 2
#define SEQ 2048
#define DIM 1024
#define NH 32
#define HDIM 32

#define LDP 72  // attn P-tile LDS row stride (144B: 16B-aligned, b128 reads conflict-free)

static __device__ __forceinline__ f32x4 mfma16(bf16x8 a, bf16x8 b, f32x4 c) {
    return __builtin_amdgcn_mfma_f32_16x16x32_bf16(a, b, c, 0, 0, 0);
}

// raw v_exp_f32: computes 2^x. log2(e) is pre-folded into the Q scale.
static __device__ __forceinline__ float fexp2(float x) {
    float r;
    asm("v_exp_f32 %0, %1" : "=v"(r) : "v"(x));
    return r;
}

// async global->LDS, 16B per lane; lds dest = wave-uniform base + lane*16
static __device__ __forceinline__ void load_lds16(const bf16_t* g, bf16_t* l) {
    __builtin_amdgcn_global_load_lds(
        (const __attribute__((address_space(1))) void*)(g),
        (__attribute__((address_space(3))) void*)(l), 16, 0, 0);
}

// ---------------------------------------------------------------------------
// fp32 -> bf16 convert. 5 regions (x, wq, wk, wv, wo), grid-stride.
// ---------------------------------------------------------------------------
__global__ __launch_bounds__(256)
void cvt_f32_bf16(const float* __restrict__ s0, bf16_t* __restrict__ d0, int n0,
                  const float* __restrict__ s1, bf16_t* __restrict__ d1, int n1,
                  const float* __restrict__ s2, bf16_t* __restrict__ d2, int n2,
                  const float* __restrict__ s3, bf16_t* __restrict__ d3, int n3,
                  const float* __restrict__ s4, bf16_t* __restrict__ d4, int n4) {
    const int stride = gridDim.x * blockDim.x;
    const int tid = blockIdx.x * blockDim.x + threadIdx.x;
    const float* src[5] = {s0, s1, s2, s3, s4};
    bf16_t* dst[5] = {d0, d1, d2, d3, d4};
    const int n[5] = {n0, n1, n2, n3, n4};
#pragma unroll
    for (int r = 0; r < 5; r++) {
        const int nv = n[r] >> 2;
        for (int i = tid; i < nv; i += stride) {
            float4 v = ((const float4*)src[r])[i];
            bf16_t o[4] = {(bf16_t)v.x, (bf16_t)v.y, (bf16_t)v.z, (bf16_t)v.w};
            *(uint2*)(dst[r] + i * 4) = *(const uint2*)o;
        }
    }
}

// ---------------------------------------------------------------------------
// Pipelined GEMM: C = A @ W^T, all-bf16, BN=128, BK=32.
// TRIPLE-buffered LDS (stage k+2 ahead, steady-state vmcnt(8)/(6)). BOTH-SIDES
// XOR swizzle (q' = q ^ ((row>>1)&3)) on global source + LDS read: kills the
// 8-way ds_read_b128 bank conflict of the row-major [*][32] tile.
// EPI 0 (BM=64): out-proj -> fp32 C. EPI 1 (BM=128): fused QKV:
//   seg0 -> qb PRE-SCALED by slen[s]*ss[h]*log2(e)/sqrt(32), seg1 -> kb,
//   seg2 -> vtb (transposed store). XCD-swizzled 1-D grid (id&7 = XCD).
// ---------------------------------------------------------------------------
template <int EPI, int BM>
__global__ __launch_bounds__(256)
void gemm_pipe(const bf16_t* __restrict__ A, const bf16_t* __restrict__ W,
               float* __restrict__ Cf, bf16_t* __restrict__ qb,
               bf16_t* __restrict__ kb, bf16_t* __restrict__ vtb,
               const float* __restrict__ slen, const float* __restrict__ ss) {
    constexpr int MI = BM / 32;      // m-frags per wave
    constexpr int ABUF = BM * 32;    // elems per A stage buffer
    __shared__ alignas(16) bf16_t As[3 * ABUF];
    __shared__ alignas(16) bf16_t Bs[3 * 4096];
    const int t = threadIdx.x;
    const int lane = t & 63, wave = t >> 6;
    const int lane16 = lane & 15, quad = lane >> 4;
    const int wm = (wave >> 1) * (BM / 2), wn = (wave & 1) * 64;
    const int id = blockIdx.x;
    int m0, n0g;
    if (EPI == 1) {  // 768 = 8 xcd * 4 mslot * 24 n
        const int xcd = id & 7, slot = id >> 3;
        m0 = (xcd + 8 * (slot & 3)) * 128;
        n0g = (slot >> 2) * 128;
    } else {  // 512 = 8 xcd * 8 mslot * 8 n
        const int xcd = id & 7, slot = id >> 3;
        m0 = (xcd + 8 * (slot & 7)) * 64;
        n0g = (slot >> 3) * 128;
    }
    const int tr = t >> 2;                        // 0..63 (LDS chunk row)
    const int tc = ((t & 3) ^ ((tr >> 1) & 3)) * 8;  // SWIZZLED source quad
    const bf16_t* ga = A + (m0 + tr) * DIM + tc;
    const bf16_t* gb = W + (n0g + tr) * DIM + tc;
    const int rq = (quad ^ ((lane16 >> 1) & 3)) * 8;  // read-side involution
    const bool vseg = (EPI == 1) && (n0g >= 2048);

    f32x4 acc[MI][4];
#pragma unroll
    for (int i = 0; i < MI; i++)
#pragma unroll
        for (int j = 0; j < 4; j++) acc[i][j] = f32x4{0.f, 0.f, 0.f, 0.f};

    auto stage = [&](int k0, int buf) {
        bf16_t* a_dst = As + buf * ABUF + (t & 192) * 8;
        bf16_t* b_dst = Bs + buf * 4096 + (t & 192) * 8;
        load_lds16(ga + k0, a_dst);
        if (BM == 128) load_lds16(ga + 64 * DIM + k0, a_dst + 2048);
        load_lds16(gb + k0, b_dst);
        load_lds16(gb + 64 * DIM + k0, b_dst + 2048);
    };
    auto compute = [&](int buf) {
        bf16x8 af[MI], bfr[4];
#pragma unroll
        for (int mi = 0; mi < MI; mi++)
            af[mi] = *(const bf16x8*)(As + buf * ABUF +
                                      (wm + mi * 16 + lane16) * 32 + rq);
#pragma unroll
        for (int ni = 0; ni < 4; ni++)
            bfr[ni] = *(const bf16x8*)(Bs + buf * 4096 +
                                       (wn + ni * 16 + lane16) * 32 + rq);
        if (vseg) {
#pragma unroll
            for (int mi = 0; mi < MI; mi++)
#pragma unroll
                for (int ni = 0; ni < 4; ni++)
                    acc[mi][ni] = mfma16(bfr[ni], af[mi], acc[mi][ni]);
        } else {
#pragma unroll
            for (int mi = 0; mi < MI; mi++)
#pragma unroll
                for (int ni = 0; ni < 4; ni++)
                    acc[mi][ni] = mfma16(af[mi], bfr[ni], acc[mi][ni]);
        }
    };

    stage(0, 0);
    stage(32, 1);
#pragma unroll
    for (int k0 = 0; k0 < DIM; k0 += 32) {
        const int it = k0 >> 5;
        const int cur = it % 3;
        if (k0 + 64 < DIM) {
            stage(k0 + 64, (it + 2) % 3);
            if (BM == 128)
                asm volatile("s_waitcnt vmcnt(8)" ::: "memory");
            else
                asm volatile("s_waitcnt vmcnt(6)" ::: "memory");
        } else if (k0 + 32 < DIM) {
            if (BM == 128)
                asm volatile("s_waitcnt vmcnt(4)" ::: "memory");
            else
                asm volatile("s_waitcnt vmcnt(3)" ::: "memory");
        } else {
            asm volatile("s_waitcnt vmcnt(0)" ::: "memory");
        }
        asm volatile("s_barrier" ::: "memory");
        compute(cur);
        if (k0 + 32 < DIM) {
            asm volatile("s_waitcnt lgkmcnt(0)" ::: "memory");
            asm volatile("s_barrier" ::: "memory");  // reads done; safe to overwrite
        }
    }

    if (EPI == 0) {
#pragma unroll
        for (int mi = 0; mi < MI; mi++)
#pragma unroll
            for (int ni = 0; ni < 4; ni++)
#pragma unroll
                for (int r = 0; r < 4; r++) {
                    int row = m0 + wm + mi * 16 + quad * 4 + r;
                    int col = n0g + wn + ni * 16 + lane16;
                    Cf[row * DIM + col] = acc[mi][ni][r];
                }
    } else if (!vseg) {
        const bool isq = (n0g < 1024);
        bf16_t* dst = isq ? qb : kb;
        const int nb = n0g & 1023;
#pragma unroll
        for (int mi = 0; mi < MI; mi++)
#pragma unroll
            for (int ni = 0; ni < 4; ni++) {
                const int h = ((nb + wn) >> 5) + (ni >> 1);  // lane-uniform
                // 1/sqrt(32) * log2(e): attn uses v_exp_f32 (2^x) directly
                const float hscale =
                    isq ? ss[h] * (0.17677669529663687f * 1.4426950408889634f)
                        : 0.f;
#pragma unroll
                for (int r = 0; r < 4; r++) {
                    int m = m0 + wm + mi * 16 + quad * 4 + r;  // b*SEQ+s
                    int nl = nb + wn + ni * 16 + lane16;       // h*HDIM+hd
                    int b = m >> 11, s = m & (SEQ - 1);
                    int d = nl & 31;
                    float v = acc[mi][ni][r];
                    if (isq) v *= slen[s] * hscale;  // folded SSMax scale
                    dst[(((b * NH + h) << 11) + s) * 32 + d] = (bf16_t)v;
                }
            }
    } else {  // V: acc = C^T tile; row(quad,r)=n(hd), col(lane16)=m(s)
        const int nb = n0g & 1023;
#pragma unroll
        for (int mi = 0; mi < MI; mi++)
#pragma unroll
            for (int ni = 0; ni < 4; ni++)
#pragma unroll
                for (int r = 0; r < 4; r++) {
                    int nl = nb + wn + ni * 16 + quad * 4 + r;  // h*HDIM+hd
                    int m = m0 + wm + mi * 16 + lane16;         // b*SEQ+s
                    int b = m >> 11, s = m & (SEQ - 1);
                    int h = nl >> 5, d = nl & 31;
                    vtb[(((b * NH + h) << 5) + d) * SEQ + s] = (bf16_t)acc[mi][ni][r];
                }
    }
}

// ---------------------------------------------------------------------------
// Flash attention, causal, SSMax+log2e PRE-FOLDED INTO Q (v_exp_f32 = 2^x).
// No online max. KVBLK=64, software-pipelined P (double-buffered LDS),
// l via ones-column MFMA. Complement-paired per-SIMD balance (R6, passing).
// R8: 2-DEEP K PREFETCH, copy-style (minimal diff vs R6): consume set kc,
// prefetch set kn. Per iteration: qkexp(kc=K(i)) -> kcopy (kc<-kn, v_movs)
// -> issue kn=K(i+2). The vmcnt wait on K moves from ~250cyc after issue
// (R6: less than HBM latency ~900cyc -> every wave stalled each iter) to a
// full iteration (~1300cyc) after issue. Prefetch index CLAMPED to nb64-1:
// zero out-of-range reads (clamped loads are dup in-bounds, never consumed).
// No parity branches, no reference-param lambdas (R7's tainted pattern).
// ---------------------------------------------------------------------------
__global__ __launch_bounds__(512, 4)
void attn_fwd(const bf16_t* __restrict__ q, const bf16_t* __restrict__ k,
              const bf16_t* __restrict__ vt, bf16_t* __restrict__ out) {
    __shared__ alignas(16) bf16_t pscr[8][2][32 * LDP];  // 72 KB
    const int t = threadIdx.x;
    const int lane = t & 63, wave = t >> 6;  // wave 0..7
    const int lane16 = lane & 15, quad = lane >> 4;
    // complement-paired work map (dispatch-agnostic per-SIMD balance)
    const int g = blockIdx.x & 7;
    const int bh = blockIdx.x >> 3;          // 0..63
    const int tb = g * 4 + (wave & 3);       // 0..31
    const int qt = (wave < 4) ? tb : (63 - tb);
    const int h = bh & (NH - 1);
    const int b = bh >> 5;
    const int q0 = qt * 32;
    const bf16_t* qh = q + (b * NH + h) * SEQ * HDIM;
    const bf16_t* kh = k + (b * NH + h) * SEQ * HDIM;
    const bf16_t* vth = vt + (b * NH + h) * HDIM * SEQ;

    // P LDS: write row = mi*16+quad*4+r, col = 4*l16 + {0..3} (tile t = col%4);
    // read row = lane16 (+16), cols quad*8..+7 (+32 for key-half 1).
    bf16_t* wb0 = pscr[wave][0] + quad * 4 * LDP + 4 * lane16;
    bf16_t* wb1 = pscr[wave][1] + quad * 4 * LDP + 4 * lane16;
    const bf16_t* rb0 = pscr[wave][0] + lane16 * LDP + quad * 8;
    const bf16_t* rb1 = pscr[wave][1] + lane16 * LDP + quad * 8;

    bf16x8 qf[2];
    qf[0] = *(const bf16x8*)(qh + (q0 + lane16) * HDIM + quad * 8);
    qf[1] = *(const bf16x8*)(qh + (q0 + 16 + lane16) * HDIM + quad * 8);

    bf16x8 ones;
#pragma unroll
    for (int j = 0; j < 8; j++) ones[j] = (bf16_t)1.0f;

    f32x4 o[2][2], ol[2];
#pragma unroll
    for (int mi = 0; mi < 2; mi++) {
        ol[mi] = f32x4{0.f, 0.f, 0.f, 0.f};
#pragma unroll
        for (int ni = 0; ni < 2; ni++) o[mi][ni] = f32x4{0.f, 0.f, 0.f, 0.f};
    }

    // K: 4-strided tiles; lane reads K rows 4*l16+t (t=0..3 via imm offset)
    const bf16_t* kp0 = kh + (4 * lane16) * HDIM + quad * 8;
    const bf16_t* vpa = vth + lane16 * SEQ + quad * 8;
    const bf16_t* vpb = vth + (16 + lane16) * SEQ + quad * 8;

    const f32x4 zz = f32x4{0.f, 0.f, 0.f, 0.f};
    bf16x8 kc[4], kn[4], vc[4], pf[2][2];

    const int nb64 = (qt >> 1) + 1;  // 64-wide kv blocks (last = diagonal)
    const int jmax = nb64 - 1;       // last valid K block index (clamp)

    // qk round hh (tiles t=2hh, 2hh+1), exp + write to LDS buffer wb
    auto qkexp = [&](int hh, bf16_t* wb, int kv, bool domask) {
        f32x4 sc[2][2];
        __builtin_amdgcn_s_setprio(1);
#pragma unroll
        for (int mi = 0; mi < 2; mi++)
#pragma unroll
            for (int j = 0; j < 2; j++)
                sc[mi][j] = mfma16(qf[mi], kc[2 * hh + j], zz);
        __builtin_amdgcn_s_setprio(0);
#pragma unroll
        for (int mi = 0; mi < 2; mi++)
#pragma unroll
            for (int r = 0; r < 4; r++) {
                float p0 = fexp2(sc[mi][0][r]);  // key kv+4*l16+2hh
                float p1 = fexp2(sc[mi][1][r]);  // key kv+4*l16+2hh+1
                if (domask) {
                    const int rowg = q0 + mi * 16 + quad * 4 + r;
                    if (kv + 4 * lane16 + 2 * hh > rowg) p0 = 0.f;
                    if (kv + 4 * lane16 + 2 * hh + 1 > rowg) p1 = 0.f;
                }
                bf16_t pb[2] = {(bf16_t)p0, (bf16_t)p1};
                *(unsigned int*)(wb + (mi * 16 + r) * LDP + 2 * hh) =
                    *(const unsigned int*)pb;
            }
    };
    auto ldkc = [&](int j) {  // K block j -> kc (prologue only)
        const bf16_t* s = kp0 + j * (64 * HDIM);
#pragma unroll
        for (int tt = 0; tt < 4; tt++) kc[tt] = *(const bf16x8*)(s + tt * HDIM);
    };
    auto ldkn = [&](int j) {  // K block j -> kn (prefetch; j pre-clamped)
        const bf16_t* s = kp0 + j * (64 * HDIM);
#pragma unroll
        for (int tt = 0; tt < 4; tt++) kn[tt] = *(const bf16x8*)(s + tt * HDIM);
    };
    auto kcopy = [&]() {  // kc <- kn (VALU moves; waits kn's loads here)
#pragma unroll
        for (int tt = 0; tt < 4; tt++) kc[tt] = kn[tt];
    };
    auto ldv = [&](int kv) {  // V(kv) -> vc
        vc[0] = *(const bf16x8*)(vpa + kv);
        vc[1] = *(const bf16x8*)(vpa + kv + 32);
        vc[2] = *(const bf16x8*)(vpb + kv);
        vc[3] = *(const bf16x8*)(vpb + kv + 32);
    };
    auto ldp = [&](const bf16_t* rb) {
#pragma unroll
        for (int mi = 0; mi < 2; mi++) {
            pf[mi][0] = *(const bf16x8*)(rb + mi * 16 * LDP);
            pf[mi][1] = *(const bf16x8*)(rb + mi * 16 * LDP + 32);
        }
    };
    auto pv = [&]() {
        __builtin_amdgcn_s_setprio(1);
#pragma unroll
        for (int mi = 0; mi < 2; mi++) {
#pragma unroll
            for (int ni = 0; ni < 2; ni++) {
                o[mi][ni] = mfma16(pf[mi][0], vc[2 * ni], o[mi][ni]);
                o[mi][ni] = mfma16(pf[mi][1], vc[2 * ni + 1], o[mi][ni]);
            }
            ol[mi] = mfma16(pf[mi][0], ones, ol[mi]);
            ol[mi] = mfma16(pf[mi][1], ones, ol[mi]);
        }
        __builtin_amdgcn_s_setprio(0);
    };

    // ---- prologue: K(0)->kc, V(0), K(1)->kn; qk(K0)+exp+write buf0;
    //      kc <- K(1); issue kn = K(2)   (all prefetch indices clamped)
    ldkc(0);                         // K(0)
    ldv(0);                          // V(0)
    ldkn(1 <= jmax ? 1 : jmax);      // K(1) (dup K(0) if nb64==1)
    {
        const bool m0only = (nb64 == 1);
        qkexp(0, wb0, 0, m0only);
        qkexp(1, wb0, 0, m0only);
        kcopy();                     // kc = K(1)
        ldkn(2 <= jmax ? 2 : jmax);  // K(2) clamped
    }

    // ---- main loop i = 1..nb64-2: kc holds K(i); after consume,
    //      kc <- K(i+1) (from kn), issue kn = K(i+2) clamped
    for (int i = 1; i < nb64 - 1; i++) {
        const int kv = i << 6;
        bf16_t* wb = (i & 1) ? wb1 : wb0;
        const bf16_t* rb = (i & 1) ? rb0 : rb1;
        ldp(rb);        // P(i-1): in-order LDS, after prev writes
        pv();           // P(i-1) x V(i-1); vc regs now dead
        ldv(kv);        // V(i) into vc
        qkexp(0, wb, kv, false);
        qkexp(1, wb, kv, false);
        kcopy();        // kc = K(i+1), issued a full iteration ago
        ldkn(i + 2 <= jmax ? i + 2 : jmax);  // K(i+2) clamped
    }

    // ---- tail i = nb64-1 (masked diagonal), if nb64 >= 2; kc = K(nb64-1)
    if (nb64 > 1) {
        const int i = nb64 - 1;
        const int kv = i << 6;
        bf16_t* wb = (i & 1) ? wb1 : wb0;
        const bf16_t* rb = (i & 1) ? rb0 : rb1;
        ldp(rb);
        pv();
        ldv(kv);
        qkexp(0, wb, kv, true);
        qkexp(1, wb, kv, true);
    }

    // ---- epilogue: last P tile
    ldp(((nb64 - 1) & 1) ? rb1 : rb0);
    pv();

    // ---- normalize + store: l = ol[mi][r] (replicated across lane16)
#pragma unroll
    for (int mi = 0; mi < 2; mi++)
#pragma unroll
        for (int r = 0; r < 4; r++) {
            float inv = 1.0f / ol[mi][r];
            int qi = q0 + mi * 16 + quad * 4 + r;
            bf16_t* ob = out + (b * SEQ + qi) * DIM + h * HDIM;
            ob[lane16] = (bf16_t)(o[mi][0][r] * inv);
            ob[16 + lane16] = (bf16_t)(o[mi][1][r] * inv);
        }
}

extern "C" void kernel_launch(void* const* d_in, const int* in_sizes, int n_in,
                              void* d_out, int out_size, void* d_ws, size_t ws_size,
                              hipStream_t stream) {
    // input order: x, mask, section_log_len, wq, wk, wv, wo, seq_scale
    // dtype model (verified): fp32 I/O, bf16 internal compute.
    const float* x = (const float*)d_in[0];
    const float* slen = (const float*)d_in[2];
    const float* wq = (const float*)d_in[3];
    const float* wk = (const float*)d_in[4];
    const float* wv = (const float*)d_in[5];
    const float* wo = (const float*)d_in[6];
    const float* ss = (const float*)d_in[7];

    const size_t ELEMS = (size_t)NB * SEQ * DIM;  // 4 Mi elems
    const size_t WELEMS = (size_t)DIM * DIM;      // 1 Mi elems
    // ws layout (bf16 elems), 32 MB:
    bf16_t* xb = (bf16_t*)d_ws;           // phase 1: bf16 x
    bf16_t* abuf = xb;                    // phase 2: attn out
    bf16_t* wqkvb = xb + ELEMS;           // packed [wq;wk;wv], N=3072
    bf16_t* wob = wqkvb + 3 * WELEMS;
    bf16_t* qbuf = wob + WELEMS;          // (B,H,S,HD), PRE-SCALED (incl log2e)
    bf16_t* vtbuf = qbuf + ELEMS;         // (B,H,HD,S)
    bf16_t* kbuf = (bf16_t*)d_out;        // 8 MB of 16 MB fp32 out (scratch)

    dim3 blk(256);
    cvt_f32_bf16<<<dim3(1024), blk, 0, stream>>>(
        x, xb, (int)ELEMS, wq, wqkvb, (int)WELEMS, wk, wqkvb + WELEMS,
        (int)WELEMS, wv, wqkvb + 2 * WELEMS, (int)WELEMS, wo, wob, (int)WELEMS);

    // QKV: 768 blocks (3/CU), XCD-swizzled, 3-deep pipelined K-loop, swizzled LDS
    gemm_pipe<1, 128><<<dim3(768), blk, 0, stream>>>(
        xb, wqkvb, nullptr, qbuf, kbuf, vtbuf, slen, ss);
    // attn: 512 blocks x 512 threads, complement-paired balance, 2-deep K (copy)
    attn_fwd<<<dim3(NB * NH * (SEQ / 32) / 8), dim3(512), 0, stream>>>(
        qbuf, kbuf, vtbuf, abuf);
    // out-proj: 512 blocks (2/CU), XCD-swizzled, 3-deep pipelined K-loop
    gemm_pipe<0, 64><<<dim3(512), blk, 0, stream>>>(
        abuf, wob, (float*)d_out, nullptr, nullptr, nullptr, nullptr, nullptr);
}

// Round 9
// 210.396 us; speedup vs baseline: 1.0112x; 1.0112x over previous
//
#include <hip/hip_runtime.h>
#include <hip/hip_bf16.h>

typedef __bf16 bf16_t;
typedef bf16_t bf16x8 __attribute__((ext_vector_type(8)));
typedef float f32x4 __attribute__((ext_vector_type(4)));

#define NB 2
#define SEQ 2048
#define DIM 1024
#define NH 32
#define HDIM 32

#define LDP 72  // attn P-tile LDS row stride (144B: 16B-aligned, b128 reads conflict-free)

static __device__ __forceinline__ f32x4 mfma16(bf16x8 a, bf16x8 b, f32x4 c) {
    return __builtin_amdgcn_mfma_f32_16x16x32_bf16(a, b, c, 0, 0, 0);
}

// raw v_exp_f32: computes 2^x. log2(e) is pre-folded into the Q scale.
static __device__ __forceinline__ float fexp2(float x) {
    float r;
    asm("v_exp_f32 %0, %1" : "=v"(r) : "v"(x));
    return r;
}

// async global->LDS, 16B per lane; lds dest = wave-uniform base + lane*16
static __device__ __forceinline__ void load_lds16(const bf16_t* g, bf16_t* l) {
    __builtin_amdgcn_global_load_lds(
        (const __attribute__((address_space(1))) void*)(g),
        (__attribute__((address_space(3))) void*)(l), 16, 0, 0);
}

// ---------------------------------------------------------------------------
// fp32 -> bf16 convert. 5 regions (x, wq, wk, wv, wo), grid-stride.
// ---------------------------------------------------------------------------
__global__ __launch_bounds__(256)
void cvt_f32_bf16(const float* __restrict__ s0, bf16_t* __restrict__ d0, int n0,
                  const float* __restrict__ s1, bf16_t* __restrict__ d1, int n1,
                  const float* __restrict__ s2, bf16_t* __restrict__ d2, int n2,
                  const float* __restrict__ s3, bf16_t* __restrict__ d3, int n3,
                  const float* __restrict__ s4, bf16_t* __restrict__ d4, int n4) {
    const int stride = gridDim.x * blockDim.x;
    const int tid = blockIdx.x * blockDim.x + threadIdx.x;
    const float* src[5] = {s0, s1, s2, s3, s4};
    bf16_t* dst[5] = {d0, d1, d2, d3, d4};
    const int n[5] = {n0, n1, n2, n3, n4};
#pragma unroll
    for (int r = 0; r < 5; r++) {
        const int nv = n[r] >> 2;
        for (int i = tid; i < nv; i += stride) {
            float4 v = ((const float4*)src[r])[i];
            bf16_t o[4] = {(bf16_t)v.x, (bf16_t)v.y, (bf16_t)v.z, (bf16_t)v.w};
            *(uint2*)(dst[r] + i * 4) = *(const uint2*)o;
        }
    }
}

// ---------------------------------------------------------------------------
// Pipelined GEMM: C = A @ W^T, all-bf16, BN=128, BK=32.
// TRIPLE-buffered LDS (stage k+2 ahead, steady-state vmcnt(8)/(6)). BOTH-SIDES
// XOR swizzle (q' = q ^ ((row>>1)&3)) on global source + LDS read: kills the
// 8-way ds_read_b128 bank conflict of the row-major [*][32] tile.
// EPI 0 (BM=64): out-proj -> fp32 C. EPI 1 (BM=128): fused QKV:
//   seg0 -> qb PRE-SCALED by slen[s]*ss[h]*log2(e)/sqrt(32), seg1 -> kb,
//   seg2 -> vtb (transposed store). XCD-swizzled 1-D grid (id&7 = XCD).
// ---------------------------------------------------------------------------
template <int EPI, int BM>
__global__ __launch_bounds__(256)
void gemm_pipe(const bf16_t* __restrict__ A, const bf16_t* __restrict__ W,
               float* __restrict__ Cf, bf16_t* __restrict__ qb,
               bf16_t* __restrict__ kb, bf16_t* __restrict__ vtb,
               const float* __restrict__ slen, const float* __restrict__ ss) {
    constexpr int MI = BM / 32;      // m-frags per wave
    constexpr int ABUF = BM * 32;    // elems per A stage buffer
    __shared__ alignas(16) bf16_t As[3 * ABUF];
    __shared__ alignas(16) bf16_t Bs[3 * 4096];
    const int t = threadIdx.x;
    const int lane = t & 63, wave = t >> 6;
    const int lane16 = lane & 15, quad = lane >> 4;
    const int wm = (wave >> 1) * (BM / 2), wn = (wave & 1) * 64;
    const int id = blockIdx.x;
    int m0, n0g;
    if (EPI == 1) {  // 768 = 8 xcd * 4 mslot * 24 n
        const int xcd = id & 7, slot = id >> 3;
        m0 = (xcd + 8 * (slot & 3)) * 128;
        n0g = (slot >> 2) * 128;
    } else {  // 512 = 8 xcd * 8 mslot * 8 n
        const int xcd = id & 7, slot = id >> 3;
        m0 = (xcd + 8 * (slot & 7)) * 64;
        n0g = (slot >> 3) * 128;
    }
    const int tr = t >> 2;                        // 0..63 (LDS chunk row)
    const int tc = ((t & 3) ^ ((tr >> 1) & 3)) * 8;  // SWIZZLED source quad
    const bf16_t* ga = A + (m0 + tr) * DIM + tc;
    const bf16_t* gb = W + (n0g + tr) * DIM + tc;
    const int rq = (quad ^ ((lane16 >> 1) & 3)) * 8;  // read-side involution
    const bool vseg = (EPI == 1) && (n0g >= 2048);

    f32x4 acc[MI][4];
#pragma unroll
    for (int i = 0; i < MI; i++)
#pragma unroll
        for (int j = 0; j < 4; j++) acc[i][j] = f32x4{0.f, 0.f, 0.f, 0.f};

    auto stage = [&](int k0, int buf) {
        bf16_t* a_dst = As + buf * ABUF + (t & 192) * 8;
        bf16_t* b_dst = Bs + buf * 4096 + (t & 192) * 8;
        load_lds16(ga + k0, a_dst);
        if (BM == 128) load_lds16(ga + 64 * DIM + k0, a_dst + 2048);
        load_lds16(gb + k0, b_dst);
        load_lds16(gb + 64 * DIM + k0, b_dst + 2048);
    };
    auto compute = [&](int buf) {
        bf16x8 af[MI], bfr[4];
#pragma unroll
        for (int mi = 0; mi < MI; mi++)
            af[mi] = *(const bf16x8*)(As + buf * ABUF +
                                      (wm + mi * 16 + lane16) * 32 + rq);
#pragma unroll
        for (int ni = 0; ni < 4; ni++)
            bfr[ni] = *(const bf16x8*)(Bs + buf * 4096 +
                                       (wn + ni * 16 + lane16) * 32 + rq);
        if (vseg) {
#pragma unroll
            for (int mi = 0; mi < MI; mi++)
#pragma unroll
                for (int ni = 0; ni < 4; ni++)
                    acc[mi][ni] = mfma16(bfr[ni], af[mi], acc[mi][ni]);
        } else {
#pragma unroll
            for (int mi = 0; mi < MI; mi++)
#pragma unroll
                for (int ni = 0; ni < 4; ni++)
                    acc[mi][ni] = mfma16(af[mi], bfr[ni], acc[mi][ni]);
        }
    };

    stage(0, 0);
    stage(32, 1);
#pragma unroll
    for (int k0 = 0; k0 < DIM; k0 += 32) {
        const int it = k0 >> 5;
        const int cur = it % 3;
        if (k0 + 64 < DIM) {
            stage(k0 + 64, (it + 2) % 3);
            if (BM == 128)
                asm volatile("s_waitcnt vmcnt(8)" ::: "memory");
            else
                asm volatile("s_waitcnt vmcnt(6)" ::: "memory");
        } else if (k0 + 32 < DIM) {
            if (BM == 128)
                asm volatile("s_waitcnt vmcnt(4)" ::: "memory");
            else
                asm volatile("s_waitcnt vmcnt(3)" ::: "memory");
        } else {
            asm volatile("s_waitcnt vmcnt(0)" ::: "memory");
        }
        asm volatile("s_barrier" ::: "memory");
        compute(cur);
        if (k0 + 32 < DIM) {
            asm volatile("s_waitcnt lgkmcnt(0)" ::: "memory");
            asm volatile("s_barrier" ::: "memory");  // reads done; safe to overwrite
        }
    }

    if (EPI == 0) {
#pragma unroll
        for (int mi = 0; mi < MI; mi++)
#pragma unroll
            for (int ni = 0; ni < 4; ni++)
#pragma unroll
                for (int r = 0; r < 4; r++) {
                    int row = m0 + wm + mi * 16 + quad * 4 + r;
                    int col = n0g + wn + ni * 16 + lane16;
                    Cf[row * DIM + col] = acc[mi][ni][r];
                }
    } else if (!vseg) {
        const bool isq = (n0g < 1024);
        bf16_t* dst = isq ? qb : kb;
        const int nb = n0g & 1023;
#pragma unroll
        for (int mi = 0; mi < MI; mi++)
#pragma unroll
            for (int ni = 0; ni < 4; ni++) {
                const int h = ((nb + wn) >> 5) + (ni >> 1);  // lane-uniform
                // 1/sqrt(32) * log2(e): attn uses v_exp_f32 (2^x) directly
                const float hscale =
                    isq ? ss[h] * (0.17677669529663687f * 1.4426950408889634f)
                        : 0.f;
#pragma unroll
                for (int r = 0; r < 4; r++) {
                    int m = m0 + wm + mi * 16 + quad * 4 + r;  // b*SEQ+s
                    int nl = nb + wn + ni * 16 + lane16;       // h*HDIM+hd
                    int b = m >> 11, s = m & (SEQ - 1);
                    int d = nl & 31;
                    float v = acc[mi][ni][r];
                    if (isq) v *= slen[s] * hscale;  // folded SSMax scale
                    dst[(((b * NH + h) << 11) + s) * 32 + d] = (bf16_t)v;
                }
            }
    } else {  // V: acc = C^T tile; row(quad,r)=n(hd), col(lane16)=m(s)
        const int nb = n0g & 1023;
#pragma unroll
        for (int mi = 0; mi < MI; mi++)
#pragma unroll
            for (int ni = 0; ni < 4; ni++)
#pragma unroll
                for (int r = 0; r < 4; r++) {
                    int nl = nb + wn + ni * 16 + quad * 4 + r;  // h*HDIM+hd
                    int m = m0 + wm + mi * 16 + lane16;         // b*SEQ+s
                    int b = m >> 11, s = m & (SEQ - 1);
                    int h = nl >> 5, d = nl & 31;
                    vtb[(((b * NH + h) << 5) + d) * SEQ + s] = (bf16_t)acc[mi][ni][r];
                }
    }
}

// ---------------------------------------------------------------------------
// Flash attention, causal, SSMax+log2e PRE-FOLDED INTO Q (v_exp_f32 = 2^x).
// No online max. KVBLK=64, software-pipelined P (double-buffered LDS),
// l via ones-column MFMA, 2-deep K prefetch (copy-style, clamped).
// R9: UNIFORM WAVE DURATION. R8's tell: OccupancyPercent 30% vs 50% resident
// capacity -- complement-pairing's short waves (qt=0..3: 1-2 iters) EXIT
// early, decaying each SIMD to 1-2 long waves that execute the ~2100cyc/iter
// serial chain unoverlapped (32 iters x 2100 = 68.5us: closes). Fix: each
// wave processes BOTH tiles of the pair (tb, 63-tb) SEQUENTIALLY -- iteration
// count = (tb>>1)+((63-tb)>>1)+2 = 33 for EVERY tb. All 2048 waves identical
// length; every SIMD keeps 2 concurrent waves from t=0 to common finish.
// Per-tile body byte-level R8 (passing); only mapping + tile loop changed.
// Grid 512 x 256thr, LDS 36KB (4 blocks/CU capacity, 2 co-resident).
// ---------------------------------------------------------------------------
__global__ __launch_bounds__(256, 4)
void attn_fwd(const bf16_t* __restrict__ q, const bf16_t* __restrict__ k,
              const bf16_t* __restrict__ vt, bf16_t* __restrict__ out) {
    __shared__ alignas(16) bf16_t pscr[4][2][32 * LDP];  // 36 KB
    const int t = threadIdx.x;
    const int lane = t & 63, wave = t >> 6;  // wave 0..3
    const int lane16 = lane & 15, quad = lane >> 4;
    const int g = blockIdx.x & 7;
    const int bh = blockIdx.x >> 3;          // 0..63
    const int tb = g * 4 + wave;             // 0..31: this wave's tile pair
    const int h = bh & (NH - 1);
    const int b = bh >> 5;
    const bf16_t* qh = q + (b * NH + h) * SEQ * HDIM;
    const bf16_t* kh = k + (b * NH + h) * SEQ * HDIM;
    const bf16_t* vth = vt + (b * NH + h) * HDIM * SEQ;

    // P LDS: write row = mi*16+quad*4+r, col = 4*l16 + {0..3} (tile t = col%4);
    // read row = lane16 (+16), cols quad*8..+7 (+32 for key-half 1).
    bf16_t* wb0 = pscr[wave][0] + quad * 4 * LDP + 4 * lane16;
    bf16_t* wb1 = pscr[wave][1] + quad * 4 * LDP + 4 * lane16;
    const bf16_t* rb0 = pscr[wave][0] + lane16 * LDP + quad * 8;
    const bf16_t* rb1 = pscr[wave][1] + lane16 * LDP + quad * 8;

    // K: 4-strided tiles; lane reads K rows 4*l16+t (t=0..3 via imm offset)
    const bf16_t* kp0 = kh + (4 * lane16) * HDIM + quad * 8;
    const bf16_t* vpa = vth + lane16 * SEQ + quad * 8;
    const bf16_t* vpb = vth + (16 + lane16) * SEQ + quad * 8;

    bf16x8 ones;
#pragma unroll
    for (int j = 0; j < 8; j++) ones[j] = (bf16_t)1.0f;

    const f32x4 zz = f32x4{0.f, 0.f, 0.f, 0.f};

    // ---- two tiles per wave: qt = tb then 63-tb (33 total iters, uniform)
    for (int tp = 0; tp < 2; tp++) {
        const int qt = tp ? (63 - tb) : tb;
        const int q0 = qt * 32;
        const int nb64 = (qt >> 1) + 1;  // 64-wide kv blocks (last = diagonal)
        const int jmax = nb64 - 1;       // last valid K block index (clamp)

        bf16x8 qf[2];
        qf[0] = *(const bf16x8*)(qh + (q0 + lane16) * HDIM + quad * 8);
        qf[1] = *(const bf16x8*)(qh + (q0 + 16 + lane16) * HDIM + quad * 8);

        f32x4 o[2][2], ol[2];
#pragma unroll
        for (int mi = 0; mi < 2; mi++) {
            ol[mi] = f32x4{0.f, 0.f, 0.f, 0.f};
#pragma unroll
            for (int ni = 0; ni < 2; ni++) o[mi][ni] = f32x4{0.f, 0.f, 0.f, 0.f};
        }

        bf16x8 kc[4], kn[4], vc[4], pf[2][2];

        // qk round hh (tiles t=2hh, 2hh+1), exp + write to LDS buffer wb
        auto qkexp = [&](int hh, bf16_t* wb, int kv, bool domask) {
            f32x4 sc[2][2];
            __builtin_amdgcn_s_setprio(1);
#pragma unroll
            for (int mi = 0; mi < 2; mi++)
#pragma unroll
                for (int j = 0; j < 2; j++)
                    sc[mi][j] = mfma16(qf[mi], kc[2 * hh + j], zz);
            __builtin_amdgcn_s_setprio(0);
#pragma unroll
            for (int mi = 0; mi < 2; mi++)
#pragma unroll
                for (int r = 0; r < 4; r++) {
                    float p0 = fexp2(sc[mi][0][r]);  // key kv+4*l16+2hh
                    float p1 = fexp2(sc[mi][1][r]);  // key kv+4*l16+2hh+1
                    if (domask) {
                        const int rowg = q0 + mi * 16 + quad * 4 + r;
                        if (kv + 4 * lane16 + 2 * hh > rowg) p0 = 0.f;
                        if (kv + 4 * lane16 + 2 * hh + 1 > rowg) p1 = 0.f;
                    }
                    bf16_t pb[2] = {(bf16_t)p0, (bf16_t)p1};
                    *(unsigned int*)(wb + (mi * 16 + r) * LDP + 2 * hh) =
                        *(const unsigned int*)pb;
                }
        };
        auto ldkc = [&](int j) {  // K block j -> kc (prologue only)
            const bf16_t* s = kp0 + j * (64 * HDIM);
#pragma unroll
            for (int tt = 0; tt < 4; tt++) kc[tt] = *(const bf16x8*)(s + tt * HDIM);
        };
        auto ldkn = [&](int j) {  // K block j -> kn (prefetch; j pre-clamped)
            const bf16_t* s = kp0 + j * (64 * HDIM);
#pragma unroll
            for (int tt = 0; tt < 4; tt++) kn[tt] = *(const bf16x8*)(s + tt * HDIM);
        };
        auto kcopy = [&]() {  // kc <- kn (VALU moves; waits kn's loads here)
#pragma unroll
            for (int tt = 0; tt < 4; tt++) kc[tt] = kn[tt];
        };
        auto ldv = [&](int kv) {  // V(kv) -> vc
            vc[0] = *(const bf16x8*)(vpa + kv);
            vc[1] = *(const bf16x8*)(vpa + kv + 32);
            vc[2] = *(const bf16x8*)(vpb + kv);
            vc[3] = *(const bf16x8*)(vpb + kv + 32);
        };
        auto ldp = [&](const bf16_t* rb) {
#pragma unroll
            for (int mi = 0; mi < 2; mi++) {
                pf[mi][0] = *(const bf16x8*)(rb + mi * 16 * LDP);
                pf[mi][1] = *(const bf16x8*)(rb + mi * 16 * LDP + 32);
            }
        };
        auto pv = [&]() {
            __builtin_amdgcn_s_setprio(1);
#pragma unroll
            for (int mi = 0; mi < 2; mi++) {
#pragma unroll
                for (int ni = 0; ni < 2; ni++) {
                    o[mi][ni] = mfma16(pf[mi][0], vc[2 * ni], o[mi][ni]);
                    o[mi][ni] = mfma16(pf[mi][1], vc[2 * ni + 1], o[mi][ni]);
                }
                ol[mi] = mfma16(pf[mi][0], ones, ol[mi]);
                ol[mi] = mfma16(pf[mi][1], ones, ol[mi]);
            }
            __builtin_amdgcn_s_setprio(0);
        };

        // ---- prologue: K(0)->kc, V(0), K(1)->kn; qk(K0)+exp+write buf0;
        //      kc <- K(1); issue kn = K(2)   (all prefetch indices clamped)
        ldkc(0);                         // K(0)
        ldv(0);                          // V(0)
        ldkn(1 <= jmax ? 1 : jmax);      // K(1) (dup K(0) if nb64==1)
        {
            const bool m0only = (nb64 == 1);
            qkexp(0, wb0, 0, m0only);
            qkexp(1, wb0, 0, m0only);
            kcopy();                     // kc = K(1)
            ldkn(2 <= jmax ? 2 : jmax);  // K(2) clamped
        }

        // ---- main loop i = 1..nb64-2: kc holds K(i); after consume,
        //      kc <- K(i+1) (from kn), issue kn = K(i+2) clamped
        for (int i = 1; i < nb64 - 1; i++) {
            const int kv = i << 6;
            bf16_t* wb = (i & 1) ? wb1 : wb0;
            const bf16_t* rb = (i & 1) ? rb0 : rb1;
            ldp(rb);        // P(i-1): in-order LDS, after prev writes
            pv();           // P(i-1) x V(i-1); vc regs now dead
            ldv(kv);        // V(i) into vc
            qkexp(0, wb, kv, false);
            qkexp(1, wb, kv, false);
            kcopy();        // kc = K(i+1), issued a full iteration ago
            ldkn(i + 2 <= jmax ? i + 2 : jmax);  // K(i+2) clamped
        }

        // ---- tail i = nb64-1 (masked diagonal), if nb64 >= 2
        if (nb64 > 1) {
            const int i = nb64 - 1;
            const int kv = i << 6;
            bf16_t* wb = (i & 1) ? wb1 : wb0;
            const bf16_t* rb = (i & 1) ? rb0 : rb1;
            ldp(rb);
            pv();
            ldv(kv);
            qkexp(0, wb, kv, true);
            qkexp(1, wb, kv, true);
        }

        // ---- epilogue: last P tile
        ldp(((nb64 - 1) & 1) ? rb1 : rb0);
        pv();

        // ---- normalize + store: l = ol[mi][r] (replicated across lane16)
#pragma unroll
        for (int mi = 0; mi < 2; mi++)
#pragma unroll
            for (int r = 0; r < 4; r++) {
                float inv = 1.0f / ol[mi][r];
                int qi = q0 + mi * 16 + quad * 4 + r;
                bf16_t* ob = out + (b * SEQ + qi) * DIM + h * HDIM;
                ob[lane16] = (bf16_t)(o[mi][0][r] * inv);
                ob[16 + lane16] = (bf16_t)(o[mi][1][r] * inv);
            }
    }
}

extern "C" void kernel_launch(void* const* d_in, const int* in_sizes, int n_in,
                              void* d_out, int out_size, void* d_ws, size_t ws_size,
                              hipStream_t stream) {
    // input order: x, mask, section_log_len, wq, wk, wv, wo, seq_scale
    // dtype model (verified): fp32 I/O, bf16 internal compute.
    const float* x = (const float*)d_in[0];
    const float* slen = (const float*)d_in[2];
    const float* wq = (const float*)d_in[3];
    const float* wk = (const float*)d_in[4];
    const float* wv = (const float*)d_in[5];
    const float* wo = (const float*)d_in[6];
    const float* ss = (const float*)d_in[7];

    const size_t ELEMS = (size_t)NB * SEQ * DIM;  // 4 Mi elems
    const size_t WELEMS = (size_t)DIM * DIM;      // 1 Mi elems
    // ws layout (bf16 elems), 32 MB:
    bf16_t* xb = (bf16_t*)d_ws;           // phase 1: bf16 x
    bf16_t* abuf = xb;                    // phase 2: attn out
    bf16_t* wqkvb = xb + ELEMS;           // packed [wq;wk;wv], N=3072
    bf16_t* wob = wqkvb + 3 * WELEMS;
    bf16_t* qbuf = wob + WELEMS;          // (B,H,S,HD), PRE-SCALED (incl log2e)
    bf16_t* vtbuf = qbuf + ELEMS;         // (B,H,HD,S)
    bf16_t* kbuf = (bf16_t*)d_out;        // 8 MB of 16 MB fp32 out (scratch)

    dim3 blk(256);
    cvt_f32_bf16<<<dim3(1024), blk, 0, stream>>>(
        x, xb, (int)ELEMS, wq, wqkvb, (int)WELEMS, wk, wqkvb + WELEMS,
        (int)WELEMS, wv, wqkvb + 2 * WELEMS, (int)WELEMS, wo, wob, (int)WELEMS);

    // QKV: 768 blocks (3/CU), XCD-swizzled, 3-deep pipelined K-loop, swizzled LDS
    gemm_pipe<1, 128><<<dim3(768), blk, 0, stream>>>(
        xb, wqkvb, nullptr, qbuf, kbuf, vtbuf, slen, ss);
    // attn: 512 blocks x 256 threads; each wave runs tile pair (tb, 63-tb)
    // sequentially -> every wave exactly 33 iterations (uniform duration)
    attn_fwd<<<dim3(NB * NH * (SEQ / 32) / 8), blk, 0, stream>>>(
        qbuf, kbuf, vtbuf, abuf);
    // out-proj: 512 blocks (2/CU), XCD-swizzled, 3-deep pipelined K-loop
    gemm_pipe<0, 64><<<dim3(512), blk, 0, stream>>>(
        abuf, wob, (float*)d_out, nullptr, nullptr, nullptr, nullptr, nullptr);
}